// Round 6
// baseline (160.766 us; speedup 1.0000x reference)
//
#include <hip/hip_runtime.h>

// AntiAliasInterpolation2d: depthwise 13x13 Gaussian (separable), stride 4.
// in: (32,3,512,512) fp32 ; w: (3,1,13,13) fp32 ; out: (32,3,128,128) fp32
//
// v6: UN-FUSED two-pass through d_ws. Five fused variants all plateaued at
// ~45 us: block-local LDS tiling forces halo re-fetch (1.3-1.6x) and
// barrier-coupled load latency. Instead: two pure streaming kernels.
//  K1: horizontal stride-4 conv, 1 thread/h-output, 4 unconditional coalesced
//      float4 loads + 13 FMA + coalesced store -> hbuf (32,3,512,128) in ws.
//  K2: vertical stride-4 conv, 1 thread/output, 13 unconditional coalesced
//      loads from the 25 MB L3-resident hbuf, branch-free edge clamp+mask.
// HBM: ~100.7 rd + 25.2 wr + 6.3 wr (+ hot 25.2 rd from L3) ~= 132 MB ~ 21 us.

constexpr int CH = 3, H = 512, W = 512;
constexpr int OH = 128, OW = 128;
constexpr int KS = 13, KA = 6, STR = 4;
constexpr int HW1 = H * OW;          // h-pass outputs per (n,c): 512*128
constexpr int WCH = W / 4;           // 128 float4 chunks per input row

// ---- K1: horizontal stride-4 conv, fully streaming --------------------------
__global__ __launch_bounds__(256)
void aa_hpass(const float* __restrict__ in, const float* __restrict__ wgt,
              float* __restrict__ hbuf) {
    __shared__ float hsh[KS];
    const int gid = blockIdx.x * 256 + threadIdx.x;  // (nc*512 + ir)*128 + oc
    const int oc  = gid & (OW - 1);
    const int ir  = (gid >> 7) & (H - 1);
    const int nc  = gid >> 16;                       // uniform per block

    // Normalized 1D taps = row sums of the outer-product 2D weight.
    if (threadIdx.x < KS) {
        const float* w2 = wgt + (nc % CH) * KS * KS + (int)threadIdx.x * KS;
        float s = 0.f;
        #pragma unroll
        for (int j = 0; j < KS; ++j) s += w2[j];
        hsh[threadIdx.x] = s;
    }
    __syncthreads();

    float h[KS];
    #pragma unroll
    for (int k = 0; k < KS; ++k) h[k] = hsh[k];

    // Window cols 4*oc-6 .. 4*oc+6 live in chunks oc-2 .. oc+1.
    // 4 unconditional loads (clamped addr), consecutive lanes -> consecutive
    // chunks -> each load is a fully coalesced 1 KB wave transaction.
    const float4* row = (const float4*)(in + ((size_t)nc * H + ir) * W);
    float f[16];
    #pragma unroll
    for (int q = 0; q < 4; ++q) {
        const int cq  = oc - 2 + q;
        const int cqc = min(max(cq, 0), WCH - 1);
        const float4 c = row[cqc];
        const bool ok = (cq == cqc);
        f[4 * q + 0] = ok ? c.x : 0.f;
        f[4 * q + 1] = ok ? c.y : 0.f;
        f[4 * q + 2] = ok ? c.z : 0.f;
        f[4 * q + 3] = ok ? c.w : 0.f;
    }
    float a = 0.f;
    #pragma unroll
    for (int k = 0; k < KS; ++k) a += h[k] * f[k + 2];  // col 4oc-6+k = f[k+2]
    hbuf[gid] = a;
}

// ---- K2: vertical stride-4 conv from L3-resident hbuf -----------------------
__global__ __launch_bounds__(256)
void aa_vpass(const float* __restrict__ hbuf, const float* __restrict__ wgt,
              float* __restrict__ out) {
    __shared__ float hsh[KS];
    const int gid  = blockIdx.x * 256 + threadIdx.x;  // (nc*128 + or)*128 + oc
    const int oc   = gid & (OW - 1);
    const int orow = (gid >> 7) & (OH - 1);
    const int nc   = gid >> 14;                       // uniform per block

    if (threadIdx.x < KS) {
        const float* w2 = wgt + (nc % CH) * KS * KS + (int)threadIdx.x * KS;
        float s = 0.f;
        #pragma unroll
        for (int j = 0; j < KS; ++j) s += w2[j];
        hsh[threadIdx.x] = s;
    }
    __syncthreads();

    float h[KS];
    #pragma unroll
    for (int k = 0; k < KS; ++k) h[k] = hsh[k];

    const float* hb = hbuf + (size_t)nc * HW1;
    float a = 0.f;
    #pragma unroll
    for (int k = 0; k < KS; ++k) {                    // 13 independent loads,
        const int rr = STR * orow - KA + k;           // consecutive lanes ->
        const int rc = min(max(rr, 0), H - 1);        // consecutive addresses
        const float hk = (rr == rc) ? h[k] : 0.f;     // branch-free edge mask
        a += hk * hb[rc * OW + oc];
    }
    out[gid] = a;
}

extern "C" void kernel_launch(void* const* d_in, const int* in_sizes, int n_in,
                              void* d_out, int out_size, void* d_ws, size_t ws_size,
                              hipStream_t stream) {
    const float* in  = (const float*)d_in[0];
    const float* wgt = (const float*)d_in[1];
    float* out  = (float*)d_out;
    float* hbuf = (float*)d_ws;                       // 32*3*512*128 f32 = 25 MB

    const int n1 = 32 * CH * H * OW;                  // 6,291,456 h-outputs
    const int n2 = 32 * CH * OH * OW;                 // 1,572,864 outputs
    aa_hpass<<<n1 / 256, 256, 0, stream>>>(in, wgt, hbuf);
    aa_vpass<<<n2 / 256, 256, 0, stream>>>(hbuf, wgt, out);
}

// Round 7
// 150.540 us; speedup vs baseline: 1.0679x; 1.0679x over previous
//
#include <hip/hip_runtime.h>

// AntiAliasInterpolation2d: depthwise 13x13 Gaussian (separable), stride 4.
// in: (32,3,512,512) fp32 ; w: (3,1,13,13) fp32 ; out: (32,3,128,128) fp32
//
// v7: fused, single-group deep stream. Block = 2 halves x 128 chunk-columns;
// each half streams 41 unconditional independent float4 loads (8-row band,
// 8 rolling float4 accumulators, tap k = ir-4r resolved at compile time).
// Tile = 16 output rows -> in-block load redundancy 82/73 = 1.12x (v5: 1.56x).
// One barrier; horizontal pass reads zero-padded polyphase LDS vb[p][row][j]
// (conflict-free b32, no predication), coalesced scalar stores.

constexpr int CH = 3, H = 512, W = 512;
constexpr int OH = 128, OW = 128;
constexpr int KS = 13, KA = 6, STR = 4;
constexpr int TILE_R = 16;                     // output rows per block
constexpr int GRP = 8;                         // output rows per half
constexpr int G_ROWS = GRP * STR + (KS - STR); // 41 input rows per half
constexpr int WCH = W / 4;                     // 128 float4 chunks per row
constexpr int VBW = WCH + 4;                   // padded width (2 each side)

template <bool EDGE>
__device__ __forceinline__ void vstream(const float* __restrict__ inp, int base,
                                        int c, const float* __restrict__ h,
                                        float4* __restrict__ acc) {
    #pragma unroll
    for (int ir = 0; ir < G_ROWS; ++ir) {
        int row = base + ir;                   // wave-uniform
        float m = 1.f;
        if (EDGE) {
            const int rc = min(max(row, 0), H - 1);
            m = (row == rc) ? 1.f : 0.f;       // uniform 0/1 mask
            row = rc;
        }
        float4 v = ((const float4*)(inp + (size_t)row * W))[c];  // unconditional
        if (EDGE) { v.x *= m; v.y *= m; v.z *= m; v.w *= m; }
        #pragma unroll
        for (int r = 0; r < GRP; ++r) {
            const int k = ir - STR * r;        // compile-time resolved
            if (0 <= k && k < KS) {
                const float hk = h[k];
                acc[r].x += hk * v.x; acc[r].y += hk * v.y;
                acc[r].z += hk * v.z; acc[r].w += hk * v.w;
            }
        }
    }
}

__global__ __launch_bounds__(256)
void aa_interp_kernel(const float* __restrict__ in,
                      const float* __restrict__ wgt,
                      float* __restrict__ out) {
    __shared__ float hsh[KS];
    __shared__ float vb[STR][TILE_R][VBW];     // polyphase + pad, 33.8 KB

    const int nc  = blockIdx.y;                // fused (n, c), 0..95
    const int bi  = blockIdx.x;                // row-band 0..7
    const int r0  = bi * TILE_R;
    const int tid = threadIdx.x;

    // Normalized 1D taps = row sums of the outer-product 2D weight.
    if (tid < KS) {
        const float* w2 = wgt + (size_t)(nc % CH) * KS * KS + (size_t)tid * KS;
        float s = 0.f;
        #pragma unroll
        for (int j = 0; j < KS; ++j) s += w2[j];
        hsh[tid] = s;
    }
    // Zero the 2-chunk pads: 4 phases x 16 rows x 4 pad entries = 256 = tid.
    {
        const int p    = tid >> 6;
        const int orow = (tid >> 2) & 15;
        const int q    = tid & 3;
        vb[p][orow][(q < 2) ? q : 128 + q] = 0.f;   // j+2 in {0,1,130,131}
    }
    __syncthreads();

    float h[KS];
    #pragma unroll
    for (int k = 0; k < KS; ++k) h[k] = hsh[k];

    // ---- Phase 1: vertical stride-4 conv, 41-deep independent stream -----
    const int g = tid >> 7;                    // half 0/1 (output rows 8g..8g+7)
    const int c = tid & 127;                   // chunk column
    const float* inp = in + (size_t)nc * H * W;
    const int base = 64 * bi + 32 * g - KA;    // 4*(r0+8g) - 6

    float4 acc[GRP];
    #pragma unroll
    for (int r = 0; r < GRP; ++r) acc[r] = make_float4(0.f, 0.f, 0.f, 0.f);

    if (bi != 0 && bi != (OH / TILE_R - 1))
        vstream<false>(inp, base, c, h, acc);  // interior: branch-free
    else
        vstream<true>(inp, base, c, h, acc);   // edge: clamp + uniform mask

    #pragma unroll
    for (int r = 0; r < GRP; ++r) {            // conflict-free b32 writes
        const int orow = g * GRP + r;
        vb[0][orow][c + 2] = acc[r].x;
        vb[1][orow][c + 2] = acc[r].y;
        vb[2][orow][c + 2] = acc[r].z;
        vb[3][orow][c + 2] = acc[r].w;
    }
    __syncthreads();

    // ---- Phase 2: horizontal stride-4 conv from padded polyphase LDS -----
    // Output col oc, tap k: phase p=(k+2)&3, padded chunk idx oc+((k+2)>>2).
    float* op = out + (size_t)nc * OH * OW + (size_t)r0 * OW;
    #pragma unroll
    for (int i = 0; i < TILE_R * OW / 256; ++i) {   // 8 outputs per thread
        const int idx  = tid + 256 * i;
        const int orow = idx >> 7;
        const int oc   = idx & (OW - 1);
        float a = 0.f;
        #pragma unroll
        for (int k = 0; k < KS; ++k)
            a += h[k] * vb[(k + 2) & 3][orow][oc + ((k + 2) >> 2)];
        op[orow * OW + oc] = a;
    }
}

extern "C" void kernel_launch(void* const* d_in, const int* in_sizes, int n_in,
                              void* d_out, int out_size, void* d_ws, size_t ws_size,
                              hipStream_t stream) {
    const float* in  = (const float*)d_in[0];
    const float* wgt = (const float*)d_in[1];
    float* out = (float*)d_out;

    dim3 grid(OH / TILE_R, 32 * CH);           // (8, 96) = 768 blocks
    aa_interp_kernel<<<grid, dim3(256), 0, stream>>>(in, wgt, out);
}